// Round 17
// baseline (260.961 us; speedup 1.0000x reference)
//
#include <hip/hip_runtime.h>

#define NN 10000
#define NE 160000

#define INV8   0.35355339059327373f   // 1/sqrt(8)
#define QINV   0.125f                 // 1/sqrt(64)
#define GAIN   1.679177f
#define ISQ3   0.57735026918962576f   // 1/sqrt(3)
#define FINALS 4.8828125e-5f          // 0.1 * (1/sqrt(512)) * (1/sqrt(128)) * 0.125(=tp_w's 1/sqrt64)
#define MPSC   2.2097086912079612e-4f // 0.01 / sqrt(2048)

typedef __attribute__((ext_vector_type(8))) short bf16x8;
typedef __attribute__((ext_vector_type(4))) float f32x4;

__device__ __forceinline__ float4 ld4(const float* p){ return *(const float4*)p; }
__device__ __forceinline__ float sil(float x){ return x*GAIN/(1.f+__expf(-x)); }
__device__ __forceinline__ unsigned short f2b(float f){   // f32 -> bf16 RNE
  unsigned u = __float_as_uint(f);
  return (unsigned short)((u + 0x7FFFu + ((u>>16)&1u)) >> 16);
}
__device__ __forceinline__ float b2f(unsigned short b){
  return __uint_as_float(((unsigned)b) << 16);
}
__device__ __forceinline__ void st4b(unsigned short* p, float a, float b, float c, float d){
  unsigned long long v = (unsigned long long)f2b(a)
                       | ((unsigned long long)f2b(b) << 16)
                       | ((unsigned long long)f2b(c) << 32)
                       | ((unsigned long long)f2b(d) << 48);
  *(unsigned long long*)p = v;
}
__device__ __forceinline__ void up8(const unsigned short* p, float* f){
  const uint4 v = *(const uint4*)p;
  f[0]=__uint_as_float(v.x<<16); f[1]=__uint_as_float(v.x&0xFFFF0000u);
  f[2]=__uint_as_float(v.y<<16); f[3]=__uint_as_float(v.y&0xFFFF0000u);
  f[4]=__uint_as_float(v.z<<16); f[5]=__uint_as_float(v.z&0xFFFF0000u);
  f[6]=__uint_as_float(v.w<<16); f[7]=__uint_as_float(v.w&0xFFFF0000u);
}
#define C4(v,i) (((const float*)&(v))[i])

// ======= fused edge kernel (round-14 verbatim: MLP MFMA -> wq LDS -> combine) =======
#define WQ_STRIDE 260
__global__ __launch_bounds__(256, 2) void edge_fused_kernel(
    const float* __restrict__ efe,
    const float* __restrict__ mw1, const float* __restrict__ mw2,
    const float* __restrict__ mw3, const float* __restrict__ mw4,
    const float* __restrict__ ea, const int* __restrict__ eidx,
    const unsigned short* __restrict__ wsS, const unsigned short* __restrict__ wsR,
    float* __restrict__ out)
{
  __shared__ __align__(16) unsigned char pool[8192 + 128*WQ_STRIDE*2];
  unsigned short* W4q = (unsigned short*)pool;             // 8 KB
  unsigned short* W1t = (unsigned short*)(pool + 8192);    // 4 KB
  unsigned short* W2t = (unsigned short*)(pool + 12288);   // 8 KB
  unsigned short* W3t = (unsigned short*)(pool + 20480);   // 8 KB
  unsigned short* H   = (unsigned short*)(pool + 28672);   // 16 KB
  unsigned short* WQ  = (unsigned short*)(pool + 8192);    // 65 KB (overlaps W1t..H)

  const int tid = threadIdx.x;
  const int wv  = tid >> 6;
  const int l   = tid & 63;
  const int eb  = blockIdx.x * 128;

  #pragma unroll
  for (int it = 0; it < 16; ++it) {
    const int i = tid + 256*it, e = i >> 5, k = i & 31;
    H[e*64 + (k ^ ((e&7)<<3))] = (k < 8) ? f2b(efe[(size_t)(eb+e)*8 + k]) : 0;
  }
  #pragma unroll
  for (int it = 0; it < 8; ++it) {
    const int i = tid + 256*it, n = i >> 5, k = i & 31;
    W1t[n*32 + (k ^ ((n&3)<<3))] = (k < 8) ? f2b(mw1[k*64 + n]) : 0;
  }
  #pragma unroll
  for (int it = 0; it < 16; ++it) {
    const int i = tid + 256*it, k = i >> 6, n = i & 63;
    W2t[n*64 + (k ^ ((n&7)<<3))] = f2b(mw2[k*64 + n]);
    W3t[n*64 + (k ^ ((n&7)<<3))] = f2b(mw3[k*64 + n]);
  }
  __syncthreads();

  const int arow = l & 15;
  const int koff = (l >> 4) * 8;

  {
    bf16x8 a[8];
    #pragma unroll
    for (int mf = 0; mf < 8; ++mf) {
      const int e = mf*16 + arow;
      a[mf] = *(const bf16x8*)&H[e*64 + (koff ^ ((e&7)<<3))];
    }
    const int n = wv*16 + arow;
    const bf16x8 b = *(const bf16x8*)&W1t[n*32 + (koff ^ ((n&3)<<3))];
    __syncthreads();
    f32x4 acc[8];
    #pragma unroll
    for (int mf = 0; mf < 8; ++mf) {
      acc[mf] = (f32x4){0.f,0.f,0.f,0.f};
      acc[mf] = __builtin_amdgcn_mfma_f32_16x16x32_bf16(a[mf], b, acc[mf], 0, 0, 0);
    }
    #pragma unroll
    for (int mf = 0; mf < 8; ++mf)
      #pragma unroll
      for (int rg = 0; rg < 4; ++rg) {
        const int e = mf*16 + (l>>4)*4 + rg, j = wv*16 + arow;
        H[e*64 + (j ^ ((e&7)<<3))] = f2b(sil(acc[mf][rg]*INV8));
      }
    __syncthreads();
  }

  const unsigned short* Wt[2] = { W2t, W3t };
  #pragma unroll
  for (int ly = 0; ly < 2; ++ly) {
    bf16x8 a[16];
    #pragma unroll
    for (int mf = 0; mf < 8; ++mf)
      #pragma unroll
      for (int ks = 0; ks < 2; ++ks) {
        const int e = mf*16 + arow, kb = ks*32 + koff;
        a[mf*2+ks] = *(const bf16x8*)&H[e*64 + (kb ^ ((e&7)<<3))];
      }
    const int n = wv*16 + arow;
    bf16x8 b0, b1;
    {
      const int kb0 = koff, kb1 = 32 + koff;
      b0 = *(const bf16x8*)&Wt[ly][n*64 + (kb0 ^ ((n&7)<<3))];
      b1 = *(const bf16x8*)&Wt[ly][n*64 + (kb1 ^ ((n&7)<<3))];
    }
    __syncthreads();
    f32x4 acc[8];
    #pragma unroll
    for (int mf = 0; mf < 8; ++mf) {
      acc[mf] = (f32x4){0.f,0.f,0.f,0.f};
      acc[mf] = __builtin_amdgcn_mfma_f32_16x16x32_bf16(a[mf*2+0], b0, acc[mf], 0, 0, 0);
      acc[mf] = __builtin_amdgcn_mfma_f32_16x16x32_bf16(a[mf*2+1], b1, acc[mf], 0, 0, 0);
    }
    #pragma unroll
    for (int mf = 0; mf < 8; ++mf)
      #pragma unroll
      for (int rg = 0; rg < 4; ++rg) {
        const int e = mf*16 + (l>>4)*4 + rg, j = wv*16 + arow;
        H[e*64 + (j ^ ((e&7)<<3))] = f2b(sil(acc[mf][rg]*QINV));
      }
    __syncthreads();
  }

  bf16x8 a4[16];
  #pragma unroll
  for (int mf = 0; mf < 8; ++mf)
    #pragma unroll
    for (int ks = 0; ks < 2; ++ks) {
      const int e = mf*16 + arow, kb = ks*32 + koff;
      a4[mf*2+ks] = *(const bf16x8*)&H[e*64 + (kb ^ ((e&7)<<3))];
    }

  for (int q = 0; q < 4; ++q) {
    #pragma unroll
    for (int it = 0; it < 16; ++it) {
      const int i = tid + 256*it, k = i >> 6, nn = i & 63;
      W4q[nn*64 + (k ^ ((nn&7)<<3))] = f2b(mw4[k*256 + q*64 + nn]);
    }
    __syncthreads();

    const int n = wv*16 + arow;
    const bf16x8 b0 = *(const bf16x8*)&W4q[n*64 + ((koff     ) ^ ((n&7)<<3))];
    const bf16x8 b1 = *(const bf16x8*)&W4q[n*64 + ((32 + koff) ^ ((n&7)<<3))];
    f32x4 acc[8];
    #pragma unroll
    for (int mf = 0; mf < 8; ++mf) {
      acc[mf] = (f32x4){0.f,0.f,0.f,0.f};
      acc[mf] = __builtin_amdgcn_mfma_f32_16x16x32_bf16(a4[mf*2+0], b0, acc[mf], 0, 0, 0);
      acc[mf] = __builtin_amdgcn_mfma_f32_16x16x32_bf16(a4[mf*2+1], b1, acc[mf], 0, 0, 0);
    }
    #pragma unroll
    for (int mf = 0; mf < 8; ++mf)
      #pragma unroll
      for (int rg = 0; rg < 4; ++rg) {
        const int e = mf*16 + (l>>4)*4 + rg;
        const int j = q*64 + wv*16 + arow;
        WQ[e*WQ_STRIDE + j] = f2b(acc[mf][rg]);
      }
    __syncthreads();
  }

  {
    const int el  = tid >> 1;
    const int sub = tid & 1;
    const int e   = eb + el;
    const int s = eidx[e];
    const int r = eidx[NE + e];
    const float4 y = ld4(ea + (size_t)e*4);

    float accS = 0.f, accR = 0.f;
    const unsigned short* Sb = wsS + (size_t)s*768 + sub*384;
    const unsigned short* Rb = wsR + (size_t)r*768 + sub*384;
    const unsigned short* wrow = WQ + el*WQ_STRIDE;
    #pragma unroll 2
    for (int t = 0; t < 8; ++t) {
      const int uq = sub*8 + t;
      const unsigned short* Sr = Sb + t*48;
      const unsigned short* Rr = Rb + t*48;
      float S[48], R[48];
      up8(Sr+ 0, S+ 0); up8(Sr+ 8, S+ 8); up8(Sr+16, S+16);
      up8(Sr+24, S+24); up8(Sr+32, S+32); up8(Sr+40, S+40);
      up8(Rr+ 0, R+ 0); up8(Rr+ 8, R+ 8); up8(Rr+16, R+16);
      up8(Rr+24, R+24); up8(Rr+32, R+32); up8(Rr+40, R+40);

      float wq[16];
      #pragma unroll
      for (int m = 0; m < 4; ++m) {
        const unsigned long long v = *(const unsigned long long*)(wrow + m*64 + uq*4);
        #pragma unroll
        for (int d = 0; d < 4; ++d)
          wq[m*4+d] = b2f((unsigned short)(v >> (16*d)));
      }

      #pragma unroll
      for (int d = 0; d < 4; ++d) {
        const float bs = S[d]    + R[d];
        const float b0 = S[4+d]  + R[4+d];
        const float b1 = S[8+d]  + R[8+d];
        const float b2 = S[12+d] + R[12+d];
        const float bvy = b0*y.y + b1*y.z + b2*y.w;
        const float m0 = wq[d]    * bs * y.x;
        const float m1 = wq[4+d]  * bvy;
        const float m2 = wq[8+d]  * bs;
        const float m3 = wq[12+d] * y.x;
        accS += m0*S[16+d] + m1*S[20+d]
              + m2*(y.y*S[24+d] + y.z*S[28+d] + y.w*S[32+d])
              + m3*(b0*S[36+d] + b1*S[40+d] + b2*S[44+d]);
        accR += m0*R[16+d] + m1*R[20+d]
              + m2*(y.y*R[24+d] + y.z*R[28+d] + y.w*R[32+d])
              + m3*(b0*R[36+d] + b1*R[40+d] + b2*R[44+d]);
      }
    }
    float acc = FINALS * (accS + accR);
    acc += __shfl_xor(acc, 1, 64);
    if (sub == 0) {
      out[NN*4 + e] = acc;
      atomicAdd(out + (size_t)r*4, acc);
      atomicAdd(out + (size_t)s*4, -acc);
    }
  }
}

// ====== node kernel: 16-way part split (2512 waves, was 1256) ======
// Per wave-task: (node-group of 64, part p<16). Phase A: v-slice [p*4,p*4+4).
// Phase B: U-slice [p*8, p*8+8). Same record layout as before.
__global__ __launch_bounds__(256) void node_kernel(
    const float* __restrict__ nf, const float* __restrict__ ff,
    const float* __restrict__ W1s, const float* __restrict__ W1v,
    const float* __restrict__ W2s, const float* __restrict__ W2v,
    const float* __restrict__ Wvss, const float* __restrict__ Wvsv,
    const float* __restrict__ Wvrs, const float* __restrict__ Wvrv,
    const float* __restrict__ Wfs0, const float* __restrict__ Wfs1,
    const float* __restrict__ Wfr0, const float* __restrict__ Wfr1,
    const float* __restrict__ Wmsv, const float* __restrict__ Wmvs,
    unsigned short* __restrict__ wsS, unsigned short* __restrict__ wsR,
    float* __restrict__ out)
{
  const int lane = threadIdx.x & 63;
  const int Wid  = blockIdx.x * 4 + (threadIdx.x >> 6);   // grid 628 -> 2512 tasks
  const int p    = __builtin_amdgcn_readfirstlane(Wid & 15);
  const int grp  = __builtin_amdgcn_readfirstlane(Wid >> 4);
  const int n = grp * 64 + lane;
  if (n >= NN) return;
  const float* nrow = nf + (size_t)n * 256;
  const int vb = p * 4;
  const size_t rec = (size_t)n * 768;

  // ---------- phase A: l1/l2 for v in [vb, vb+4) ----------
  float a1s[4], a2s[4], a1v[3][4], a2v[3][4], t1[16];
  #pragma unroll
  for (int j = 0; j < 4; ++j){ a1s[j]=0.f; a2s[j]=0.f;
    a1v[0][j]=0.f; a1v[1][j]=0.f; a1v[2][j]=0.f;
    a2v[0][j]=0.f; a2v[1][j]=0.f; a2v[2][j]=0.f; }
  #pragma unroll
  for (int j = 0; j < 16; ++j) t1[j]=0.f;

  for (int u = 0; u < 64; ++u) {
    const float su  = nrow[u];
    const float nv0 = nrow[64+u*3+0];
    const float nv1 = nrow[64+u*3+1];
    const float nv2 = nrow[64+u*3+2];
    const float4 s1 = ld4(W1s+u*64+vb);
    const float4 s2 = ld4(W2s+u*64+vb);
    const float4 v1 = ld4(W1v+u*64+vb);
    const float4 v2 = ld4(W2v+u*64+vb);
    #pragma unroll
    for (int d = 0; d < 4; ++d) {
      a1s[d]    += su*C4(s1,d);
      a2s[d]    += su*C4(s2,d);
      a1v[0][d] += nv0*C4(v1,d); a1v[1][d] += nv1*C4(v1,d); a1v[2][d] += nv2*C4(v1,d);
      a2v[0][d] += nv0*C4(v2,d); a2v[1][d] += nv1*C4(v2,d); a2v[2][d] += nv2*C4(v2,d);
    }
    if (p == 0) {
      #pragma unroll
      for (int q = 0; q < 4; ++q) {
        const float4 m = ld4(Wmsv + u*16 + q*4);
        t1[q*4]   += su*m.x; t1[q*4+1] += su*m.y;
        t1[q*4+2] += su*m.z; t1[q*4+3] += su*m.w;
      }
    }
  }
  {
    unsigned short* S = wsS + rec + p*48;
    unsigned short* R = wsR + rec + p*48;
    st4b(S+0,  a1s[0]*QINV, a1s[1]*QINV, a1s[2]*QINV, a1s[3]*QINV);
    st4b(S+4,  a1v[0][0]*QINV, a1v[0][1]*QINV, a1v[0][2]*QINV, a1v[0][3]*QINV);
    st4b(S+8,  a1v[1][0]*QINV, a1v[1][1]*QINV, a1v[1][2]*QINV, a1v[1][3]*QINV);
    st4b(S+12, a1v[2][0]*QINV, a1v[2][1]*QINV, a1v[2][2]*QINV, a1v[2][3]*QINV);
    st4b(R+0,  a2s[0]*QINV, a2s[1]*QINV, a2s[2]*QINV, a2s[3]*QINV);
    st4b(R+4,  a2v[0][0]*QINV, a2v[0][1]*QINV, a2v[0][2]*QINV, a2v[0][3]*QINV);
    st4b(R+8,  a2v[1][0]*QINV, a2v[1][1]*QINV, a2v[1][2]*QINV, a2v[1][3]*QINV);
    st4b(R+12, a2v[2][0]*QINV, a2v[2][1]*QINV, a2v[2][2]*QINV, a2v[2][3]*QINV);
  }

  // ---------- field vectors ----------
  float fsv[16], fvv[48];
  {
    const float* fr = ff + (size_t)n*64;
    #pragma unroll
    for (int q = 0; q < 4; ++q) {
      const float4 t = ld4(fr + q*4);
      fsv[q*4]=t.x; fsv[q*4+1]=t.y; fsv[q*4+2]=t.z; fsv[q*4+3]=t.w;
    }
    #pragma unroll
    for (int q = 0; q < 12; ++q) {
      const float4 t = ld4(fr + 16 + q*4);
      fvv[q*4]=t.x; fvv[q*4+1]=t.y; fvv[q*4+2]=t.z; fvv[q*4+3]=t.w;
    }
  }

  // ---------- mp1 (p==0 only; mp0 dead) ----------
  if (p == 0) {
    float m0=0.f, m1=0.f, m2=0.f;
    #pragma unroll
    for (int v = 0; v < 16; ++v) {
      m0 += t1[v]*fvv[v*3]; m1 += t1[v]*fvv[v*3+1]; m2 += t1[v]*fvv[v*3+2];
    }
    for (int u = 0; u < 64; ++u) {
      float t2 = 0.f;
      #pragma unroll
      for (int q = 0; q < 4; ++q) {
        const float4 w = ld4(Wmvs + u*16 + q*4);
        t2 += w.x*fsv[q*4] + w.y*fsv[q*4+1] + w.z*fsv[q*4+2] + w.w*fsv[q*4+3];
      }
      m0 += nrow[64+u*3+0]*t2;
      m1 += nrow[64+u*3+1]*t2;
      m2 += nrow[64+u*3+2]*t2;
    }
    float* o = out + (size_t)n*4;
    o[0] = 0.f;
    o[1] = MPSC*m0; o[2] = MPSC*m1; o[3] = MPSC*m2;
  }

  // ---------- gs/gv prelude (replicated per part) ----------
  float gsA[16], gsB[16], gvA[48], gvB[48];
  #pragma unroll
  for (int up = 0; up < 16; ++up) {
    float sA=0.f,sB=0.f,vA0=0.f,vA1=0.f,vA2=0.f,vB0=0.f,vB1=0.f,vB2=0.f;
    #pragma unroll
    for (int q = 0; q < 4; ++q) {
      const float4 w0 = ld4(Wfs0 + up*16 + q*4);
      const float4 w1 = ld4(Wfs1 + up*16 + q*4);
      const float4 w2 = ld4(Wfr0 + up*16 + q*4);
      const float4 w3 = ld4(Wfr1 + up*16 + q*4);
      #pragma unroll
      for (int d = 0; d < 4; ++d) {
        const int v = q*4+d;
        sA  += C4(w0,d)*fsv[v];
        sB  += C4(w2,d)*fsv[v];
        vA0 += C4(w1,d)*fvv[v*3]; vA1 += C4(w1,d)*fvv[v*3+1]; vA2 += C4(w1,d)*fvv[v*3+2];
        vB0 += C4(w3,d)*fvv[v*3]; vB1 += C4(w3,d)*fvv[v*3+1]; vB2 += C4(w3,d)*fvv[v*3+2];
      }
    }
    gsA[up]=sA; gsB[up]=sB;
    gvA[up*3]=vA0; gvA[up*3+1]=vA1; gvA[up*3+2]=vA2;
    gvB[up*3]=vB0; gvB[up*3+1]=vB1; gvB[up*3+2]=vB2;
  }

  // ---------- q/r tables for U in [p*8, p*8+8) ----------
  #pragma unroll
  for (int tq = 0; tq < 2; ++tq) {
    float qa[4], qb[4], ra[3][4], rb[3][4];
    #pragma unroll
    for (int d = 0; d < 4; ++d) {
      const int U = p*8 + tq*4 + d;
      float aq=0.f,bq=0.f,a0=0.f,a1=0.f,a2=0.f,b0=0.f,b1=0.f,b2=0.f;
      #pragma unroll
      for (int q = 0; q < 4; ++q) {
        const float4 ws_ = ld4(Wvss + U*16 + q*4);
        const float4 wr_ = ld4(Wvrs + U*16 + q*4);
        const float4 wv_ = ld4(Wvsv + U*16 + q*4);
        const float4 wu_ = ld4(Wvrv + U*16 + q*4);
        #pragma unroll
        for (int dd = 0; dd < 4; ++dd) {
          const int up = q*4+dd;
          aq += C4(ws_,dd)*gsA[up];
          bq += C4(wr_,dd)*gsB[up];
          a0 += C4(wv_,dd)*gvA[up*3]; a1 += C4(wv_,dd)*gvA[up*3+1]; a2 += C4(wv_,dd)*gvA[up*3+2];
          b0 += C4(wu_,dd)*gvB[up*3]; b1 += C4(wu_,dd)*gvB[up*3+1]; b2 += C4(wu_,dd)*gvB[up*3+2];
        }
      }
      qa[d]=aq; qb[d]=bq;
      ra[0][d]=a0*ISQ3; ra[1][d]=a1*ISQ3; ra[2][d]=a2*ISQ3;
      rb[0][d]=b0*ISQ3; rb[1][d]=b1*ISQ3; rb[2][d]=b2*ISQ3;
    }
    if (p < 8) {                       // U < 64 : lo slots, uq = U>>2
      const int uq = p*2 + tq;
      unsigned short* S = wsS + rec + uq*48;
      unsigned short* R = wsR + rec + uq*48;
      st4b(S+16, qa[0],qa[1],qa[2],qa[3]);
      st4b(S+24, ra[0][0],ra[0][1],ra[0][2],ra[0][3]);
      st4b(S+28, ra[1][0],ra[1][1],ra[1][2],ra[1][3]);
      st4b(S+32, ra[2][0],ra[2][1],ra[2][2],ra[2][3]);
      st4b(R+16, qb[0],qb[1],qb[2],qb[3]);
      st4b(R+24, rb[0][0],rb[0][1],rb[0][2],rb[0][3]);
      st4b(R+28, rb[1][0],rb[1][1],rb[1][2],rb[1][3]);
      st4b(R+32, rb[2][0],rb[2][1],rb[2][2],rb[2][3]);
    } else {                           // U >= 64 : hi slots, qa gets ISQ3
      const int uq = (p-8)*2 + tq;
      unsigned short* S = wsS + rec + uq*48;
      unsigned short* R = wsR + rec + uq*48;
      st4b(S+20, qa[0]*ISQ3,qa[1]*ISQ3,qa[2]*ISQ3,qa[3]*ISQ3);
      st4b(S+36, ra[0][0],ra[0][1],ra[0][2],ra[0][3]);
      st4b(S+40, ra[1][0],ra[1][1],ra[1][2],ra[1][3]);
      st4b(S+44, ra[2][0],ra[2][1],ra[2][2],ra[2][3]);
      st4b(R+20, qb[0]*ISQ3,qb[1]*ISQ3,qb[2]*ISQ3,qb[3]*ISQ3);
      st4b(R+36, rb[0][0],rb[0][1],rb[0][2],rb[0][3]);
      st4b(R+40, rb[1][0],rb[1][1],rb[1][2],rb[1][3]);
      st4b(R+44, rb[2][0],rb[2][1],rb[2][2],rb[2][3]);
    }
  }
}

extern "C" void kernel_launch(void* const* d_in, const int* in_sizes, int n_in,
                              void* d_out, int out_size, void* d_ws, size_t ws_size,
                              hipStream_t stream) {
  (void)in_sizes; (void)n_in; (void)out_size; (void)ws_size;
  const float* node_feats  = (const float*)d_in[1];
  const float* edge_attrs  = (const float*)d_in[2];
  const float* edge_feats  = (const float*)d_in[3];
  const float* field_feats = (const float*)d_in[4];
  const int*   edge_index  = (const int*)  d_in[5];
  const float* W1s  = (const float*)d_in[6];
  const float* W1v  = (const float*)d_in[7];
  const float* W2s  = (const float*)d_in[8];
  const float* W2v  = (const float*)d_in[9];
  const float* mw1  = (const float*)d_in[10];
  const float* mw2  = (const float*)d_in[11];
  const float* mw3  = (const float*)d_in[12];
  const float* mw4  = (const float*)d_in[13];
  const float* Wvss = (const float*)d_in[14];
  const float* Wvsv = (const float*)d_in[15];
  const float* Wvrs = (const float*)d_in[16];
  const float* Wvrv = (const float*)d_in[17];
  const float* Wfs0 = (const float*)d_in[18];
  const float* Wfs1 = (const float*)d_in[19];
  const float* Wfr0 = (const float*)d_in[20];
  const float* Wfr1 = (const float*)d_in[21];
  // d_in[22]/d_in[23] feed only mp0 which charges overwrite -> dead.
  const float* Wmsv = (const float*)d_in[24];
  const float* Wmvs = (const float*)d_in[25];

  float* out = (float*)d_out;
  unsigned short* wsS = (unsigned short*)d_ws;            // NN*768 bf16 (15.36 MB)
  unsigned short* wsR = wsS + (size_t)NN*768;             // NN*768 bf16

  hipLaunchKernelGGL(node_kernel, dim3(628), dim3(256), 0, stream,
      node_feats, field_feats, W1s, W1v, W2s, W2v, Wvss, Wvsv, Wvrs, Wvrv,
      Wfs0, Wfs1, Wfr0, Wfr1, Wmsv, Wmvs, wsS, wsR, out);
  hipLaunchKernelGGL(edge_fused_kernel, dim3(NE/128), dim3(256), 0, stream,
      edge_feats, mw1, mw2, mw3, mw4, edge_attrs, edge_index, wsS, wsR, out);
}

// Round 18
// 217.477 us; speedup vs baseline: 1.1999x; 1.1999x over previous
//
#include <hip/hip_runtime.h>

#define NN 10000
#define NE 160000

#define INV8   0.35355339059327373f   // 1/sqrt(8)
#define QINV   0.125f                 // 1/sqrt(64)
#define GAIN   1.679177f
#define ISQ3   0.57735026918962576f   // 1/sqrt(3)
#define FINALS 4.8828125e-5f          // 0.1 * (1/sqrt(512)) * (1/sqrt(128)) * 0.125(=tp_w's 1/sqrt64)
#define MPSC   2.2097086912079612e-4f // 0.01 / sqrt(2048)

typedef __attribute__((ext_vector_type(8))) short bf16x8;
typedef __attribute__((ext_vector_type(4))) float f32x4;

__device__ __forceinline__ float4 ld4(const float* p){ return *(const float4*)p; }
__device__ __forceinline__ float sil(float x){ return x*GAIN/(1.f+__expf(-x)); }
__device__ __forceinline__ unsigned short f2b(float f){   // f32 -> bf16 RNE
  unsigned u = __float_as_uint(f);
  return (unsigned short)((u + 0x7FFFu + ((u>>16)&1u)) >> 16);
}
__device__ __forceinline__ float b2f(unsigned short b){
  return __uint_as_float(((unsigned)b) << 16);
}
__device__ __forceinline__ void st4b(unsigned short* p, float a, float b, float c, float d){
  unsigned long long v = (unsigned long long)f2b(a)
                       | ((unsigned long long)f2b(b) << 16)
                       | ((unsigned long long)f2b(c) << 32)
                       | ((unsigned long long)f2b(d) << 48);
  *(unsigned long long*)p = v;
}
__device__ __forceinline__ void up8(const unsigned short* p, float* f){
  const uint4 v = *(const uint4*)p;
  f[0]=__uint_as_float(v.x<<16); f[1]=__uint_as_float(v.x&0xFFFF0000u);
  f[2]=__uint_as_float(v.y<<16); f[3]=__uint_as_float(v.y&0xFFFF0000u);
  f[4]=__uint_as_float(v.z<<16); f[5]=__uint_as_float(v.z&0xFFFF0000u);
  f[6]=__uint_as_float(v.w<<16); f[7]=__uint_as_float(v.w&0xFFFF0000u);
}
#define C4(v,i) (((const float*)&(v))[i])

// ======= fused edge kernel (round-14 body + early s/r/y hoist) =======
#define WQ_STRIDE 260
__global__ __launch_bounds__(256, 2) void edge_fused_kernel(
    const float* __restrict__ efe,
    const float* __restrict__ mw1, const float* __restrict__ mw2,
    const float* __restrict__ mw3, const float* __restrict__ mw4,
    const float* __restrict__ ea, const int* __restrict__ eidx,
    const unsigned short* __restrict__ wsS, const unsigned short* __restrict__ wsR,
    float* __restrict__ out)
{
  __shared__ __align__(16) unsigned char pool[8192 + 128*WQ_STRIDE*2];
  unsigned short* W4q = (unsigned short*)pool;             // 8 KB
  unsigned short* W1t = (unsigned short*)(pool + 8192);    // 4 KB
  unsigned short* W2t = (unsigned short*)(pool + 12288);   // 8 KB
  unsigned short* W3t = (unsigned short*)(pool + 20480);   // 8 KB
  unsigned short* H   = (unsigned short*)(pool + 28672);   // 16 KB
  unsigned short* WQ  = (unsigned short*)(pool + 8192);    // 65 KB (overlaps W1t..H)

  const int tid = threadIdx.x;
  const int wv  = tid >> 6;
  const int l   = tid & 63;
  const int eb  = blockIdx.x * 128;

  // ---- combine-phase inputs hoisted: long-latency loads issued NOW,
  //      consumed ~100 µs later in the combine phase ----
  const int ce  = eb + (tid >> 1);           // this thread's combine edge
  const int cs  = eidx[ce];
  const int cr  = eidx[NE + ce];
  const float4 cy = ld4(ea + (size_t)ce*4);

  #pragma unroll
  for (int it = 0; it < 16; ++it) {
    const int i = tid + 256*it, e = i >> 5, k = i & 31;
    H[e*64 + (k ^ ((e&7)<<3))] = (k < 8) ? f2b(efe[(size_t)(eb+e)*8 + k]) : 0;
  }
  #pragma unroll
  for (int it = 0; it < 8; ++it) {
    const int i = tid + 256*it, n = i >> 5, k = i & 31;
    W1t[n*32 + (k ^ ((n&3)<<3))] = (k < 8) ? f2b(mw1[k*64 + n]) : 0;
  }
  #pragma unroll
  for (int it = 0; it < 16; ++it) {
    const int i = tid + 256*it, k = i >> 6, n = i & 63;
    W2t[n*64 + (k ^ ((n&7)<<3))] = f2b(mw2[k*64 + n]);
    W3t[n*64 + (k ^ ((n&7)<<3))] = f2b(mw3[k*64 + n]);
  }
  __syncthreads();

  const int arow = l & 15;
  const int koff = (l >> 4) * 8;

  {
    bf16x8 a[8];
    #pragma unroll
    for (int mf = 0; mf < 8; ++mf) {
      const int e = mf*16 + arow;
      a[mf] = *(const bf16x8*)&H[e*64 + (koff ^ ((e&7)<<3))];
    }
    const int n = wv*16 + arow;
    const bf16x8 b = *(const bf16x8*)&W1t[n*32 + (koff ^ ((n&3)<<3))];
    __syncthreads();
    f32x4 acc[8];
    #pragma unroll
    for (int mf = 0; mf < 8; ++mf) {
      acc[mf] = (f32x4){0.f,0.f,0.f,0.f};
      acc[mf] = __builtin_amdgcn_mfma_f32_16x16x32_bf16(a[mf], b, acc[mf], 0, 0, 0);
    }
    #pragma unroll
    for (int mf = 0; mf < 8; ++mf)
      #pragma unroll
      for (int rg = 0; rg < 4; ++rg) {
        const int e = mf*16 + (l>>4)*4 + rg, j = wv*16 + arow;
        H[e*64 + (j ^ ((e&7)<<3))] = f2b(sil(acc[mf][rg]*INV8));
      }
    __syncthreads();
  }

  const unsigned short* Wt[2] = { W2t, W3t };
  #pragma unroll
  for (int ly = 0; ly < 2; ++ly) {
    bf16x8 a[16];
    #pragma unroll
    for (int mf = 0; mf < 8; ++mf)
      #pragma unroll
      for (int ks = 0; ks < 2; ++ks) {
        const int e = mf*16 + arow, kb = ks*32 + koff;
        a[mf*2+ks] = *(const bf16x8*)&H[e*64 + (kb ^ ((e&7)<<3))];
      }
    const int n = wv*16 + arow;
    bf16x8 b0, b1;
    {
      const int kb0 = koff, kb1 = 32 + koff;
      b0 = *(const bf16x8*)&Wt[ly][n*64 + (kb0 ^ ((n&7)<<3))];
      b1 = *(const bf16x8*)&Wt[ly][n*64 + (kb1 ^ ((n&7)<<3))];
    }
    __syncthreads();
    f32x4 acc[8];
    #pragma unroll
    for (int mf = 0; mf < 8; ++mf) {
      acc[mf] = (f32x4){0.f,0.f,0.f,0.f};
      acc[mf] = __builtin_amdgcn_mfma_f32_16x16x32_bf16(a[mf*2+0], b0, acc[mf], 0, 0, 0);
      acc[mf] = __builtin_amdgcn_mfma_f32_16x16x32_bf16(a[mf*2+1], b1, acc[mf], 0, 0, 0);
    }
    #pragma unroll
    for (int mf = 0; mf < 8; ++mf)
      #pragma unroll
      for (int rg = 0; rg < 4; ++rg) {
        const int e = mf*16 + (l>>4)*4 + rg, j = wv*16 + arow;
        H[e*64 + (j ^ ((e&7)<<3))] = f2b(sil(acc[mf][rg]*QINV));
      }
    __syncthreads();
  }

  bf16x8 a4[16];
  #pragma unroll
  for (int mf = 0; mf < 8; ++mf)
    #pragma unroll
    for (int ks = 0; ks < 2; ++ks) {
      const int e = mf*16 + arow, kb = ks*32 + koff;
      a4[mf*2+ks] = *(const bf16x8*)&H[e*64 + (kb ^ ((e&7)<<3))];
    }

  for (int q = 0; q < 4; ++q) {
    #pragma unroll
    for (int it = 0; it < 16; ++it) {
      const int i = tid + 256*it, k = i >> 6, nn = i & 63;
      W4q[nn*64 + (k ^ ((nn&7)<<3))] = f2b(mw4[k*256 + q*64 + nn]);
    }
    __syncthreads();

    const int n = wv*16 + arow;
    const bf16x8 b0 = *(const bf16x8*)&W4q[n*64 + ((koff     ) ^ ((n&7)<<3))];
    const bf16x8 b1 = *(const bf16x8*)&W4q[n*64 + ((32 + koff) ^ ((n&7)<<3))];
    f32x4 acc[8];
    #pragma unroll
    for (int mf = 0; mf < 8; ++mf) {
      acc[mf] = (f32x4){0.f,0.f,0.f,0.f};
      acc[mf] = __builtin_amdgcn_mfma_f32_16x16x32_bf16(a4[mf*2+0], b0, acc[mf], 0, 0, 0);
      acc[mf] = __builtin_amdgcn_mfma_f32_16x16x32_bf16(a4[mf*2+1], b1, acc[mf], 0, 0, 0);
    }
    #pragma unroll
    for (int mf = 0; mf < 8; ++mf)
      #pragma unroll
      for (int rg = 0; rg < 4; ++rg) {
        const int e = mf*16 + (l>>4)*4 + rg;
        const int j = q*64 + wv*16 + arow;
        WQ[e*WQ_STRIDE + j] = f2b(acc[mf][rg]);
      }
    __syncthreads();
  }

  // ---- combine phase: 2 threads/edge, wq from LDS (s/r/y preloaded) ----
  {
    const int el  = tid >> 1;
    const int sub = tid & 1;
    const int e   = ce;
    const int s = cs;
    const int r = cr;
    const float4 y = cy;

    float accS = 0.f, accR = 0.f;
    const unsigned short* Sb = wsS + (size_t)s*768 + sub*384;
    const unsigned short* Rb = wsR + (size_t)r*768 + sub*384;
    const unsigned short* wrow = WQ + el*WQ_STRIDE;
    #pragma unroll 2
    for (int t = 0; t < 8; ++t) {
      const int uq = sub*8 + t;
      const unsigned short* Sr = Sb + t*48;
      const unsigned short* Rr = Rb + t*48;
      float S[48], R[48];
      up8(Sr+ 0, S+ 0); up8(Sr+ 8, S+ 8); up8(Sr+16, S+16);
      up8(Sr+24, S+24); up8(Sr+32, S+32); up8(Sr+40, S+40);
      up8(Rr+ 0, R+ 0); up8(Rr+ 8, R+ 8); up8(Rr+16, R+16);
      up8(Rr+24, R+24); up8(Rr+32, R+32); up8(Rr+40, R+40);

      float wq[16];
      #pragma unroll
      for (int m = 0; m < 4; ++m) {
        const unsigned long long v = *(const unsigned long long*)(wrow + m*64 + uq*4);
        #pragma unroll
        for (int d = 0; d < 4; ++d)
          wq[m*4+d] = b2f((unsigned short)(v >> (16*d)));
      }

      #pragma unroll
      for (int d = 0; d < 4; ++d) {
        const float bs = S[d]    + R[d];
        const float b0 = S[4+d]  + R[4+d];
        const float b1 = S[8+d]  + R[8+d];
        const float b2 = S[12+d] + R[12+d];
        const float bvy = b0*y.y + b1*y.z + b2*y.w;
        const float m0 = wq[d]    * bs * y.x;
        const float m1 = wq[4+d]  * bvy;
        const float m2 = wq[8+d]  * bs;
        const float m3 = wq[12+d] * y.x;
        accS += m0*S[16+d] + m1*S[20+d]
              + m2*(y.y*S[24+d] + y.z*S[28+d] + y.w*S[32+d])
              + m3*(b0*S[36+d] + b1*S[40+d] + b2*S[44+d]);
        accR += m0*R[16+d] + m1*R[20+d]
              + m2*(y.y*R[24+d] + y.z*R[28+d] + y.w*R[32+d])
              + m3*(b0*R[36+d] + b1*R[40+d] + b2*R[44+d]);
      }
    }
    float acc = FINALS * (accS + accR);
    acc += __shfl_xor(acc, 1, 64);
    if (sub == 0) {
      out[NN*4 + e] = acc;
      atomicAdd(out + (size_t)r*4, acc);
      atomicAdd(out + (size_t)s*4, -acc);
    }
  }
}

// ============ node kernel (round-8 verbatim, 8-way parts — proven 73 µs) ============
__global__ __launch_bounds__(256) void node_kernel(
    const float* __restrict__ nf, const float* __restrict__ ff,
    const float* __restrict__ W1s, const float* __restrict__ W1v,
    const float* __restrict__ W2s, const float* __restrict__ W2v,
    const float* __restrict__ Wvss, const float* __restrict__ Wvsv,
    const float* __restrict__ Wvrs, const float* __restrict__ Wvrv,
    const float* __restrict__ Wfs0, const float* __restrict__ Wfs1,
    const float* __restrict__ Wfr0, const float* __restrict__ Wfr1,
    const float* __restrict__ Wmsv, const float* __restrict__ Wmvs,
    unsigned short* __restrict__ wsS, unsigned short* __restrict__ wsR,
    float* __restrict__ out)
{
  const int lane = threadIdx.x & 63;
  const int Wid  = blockIdx.x * 4 + (threadIdx.x >> 6);
  const int p    = __builtin_amdgcn_readfirstlane(Wid & 7);
  const int grp  = __builtin_amdgcn_readfirstlane(Wid >> 3);
  const int n = grp * 64 + lane;
  if (n >= NN) return;
  const float* nrow = nf + (size_t)n * 256;
  const int vb = p * 8;
  const size_t rec = (size_t)n * 768;

  float a1s[8], a2s[8], a1v[3][8], a2v[3][8], t1[16];
  #pragma unroll
  for (int j = 0; j < 8; ++j){ a1s[j]=0.f; a2s[j]=0.f;
    a1v[0][j]=0.f; a1v[1][j]=0.f; a1v[2][j]=0.f;
    a2v[0][j]=0.f; a2v[1][j]=0.f; a2v[2][j]=0.f; }
  #pragma unroll
  for (int j = 0; j < 16; ++j) t1[j]=0.f;

  for (int u = 0; u < 64; ++u) {
    const float su  = nrow[u];
    const float nv0 = nrow[64+u*3+0];
    const float nv1 = nrow[64+u*3+1];
    const float nv2 = nrow[64+u*3+2];
    const float4 s1a = ld4(W1s+u*64+vb), s1b = ld4(W1s+u*64+vb+4);
    const float4 s2a = ld4(W2s+u*64+vb), s2b = ld4(W2s+u*64+vb+4);
    const float4 v1a = ld4(W1v+u*64+vb), v1b = ld4(W1v+u*64+vb+4);
    const float4 v2a = ld4(W2v+u*64+vb), v2b = ld4(W2v+u*64+vb+4);
    #pragma unroll
    for (int d = 0; d < 4; ++d) {
      a1s[d]     += su*C4(s1a,d);  a1s[4+d]     += su*C4(s1b,d);
      a2s[d]     += su*C4(s2a,d);  a2s[4+d]     += su*C4(s2b,d);
      a1v[0][d]  += nv0*C4(v1a,d); a1v[0][4+d]  += nv0*C4(v1b,d);
      a1v[1][d]  += nv1*C4(v1a,d); a1v[1][4+d]  += nv1*C4(v1b,d);
      a1v[2][d]  += nv2*C4(v1a,d); a1v[2][4+d]  += nv2*C4(v1b,d);
      a2v[0][d]  += nv0*C4(v2a,d); a2v[0][4+d]  += nv0*C4(v2b,d);
      a2v[1][d]  += nv1*C4(v2a,d); a2v[1][4+d]  += nv1*C4(v2b,d);
      a2v[2][d]  += nv2*C4(v2a,d); a2v[2][4+d]  += nv2*C4(v2b,d);
    }
    if (p == 0) {
      #pragma unroll
      for (int q = 0; q < 4; ++q) {
        const float4 m = ld4(Wmsv + u*16 + q*4);
        t1[q*4]   += su*m.x; t1[q*4+1] += su*m.y;
        t1[q*4+2] += su*m.z; t1[q*4+3] += su*m.w;
      }
    }
  }
  #pragma unroll
  for (int hh = 0; hh < 2; ++hh) {
    const int uq = 2*p + hh, o = hh*4;
    unsigned short* S = wsS + rec + uq*48;
    unsigned short* R = wsR + rec + uq*48;
    st4b(S+0,  a1s[o]*QINV, a1s[o+1]*QINV, a1s[o+2]*QINV, a1s[o+3]*QINV);
    st4b(S+4,  a1v[0][o]*QINV, a1v[0][o+1]*QINV, a1v[0][o+2]*QINV, a1v[0][o+3]*QINV);
    st4b(S+8,  a1v[1][o]*QINV, a1v[1][o+1]*QINV, a1v[1][o+2]*QINV, a1v[1][o+3]*QINV);
    st4b(S+12, a1v[2][o]*QINV, a1v[2][o+1]*QINV, a1v[2][o+2]*QINV, a1v[2][o+3]*QINV);
    st4b(R+0,  a2s[o]*QINV, a2s[o+1]*QINV, a2s[o+2]*QINV, a2s[o+3]*QINV);
    st4b(R+4,  a2v[0][o]*QINV, a2v[0][o+1]*QINV, a2v[0][o+2]*QINV, a2v[0][o+3]*QINV);
    st4b(R+8,  a2v[1][o]*QINV, a2v[1][o+1]*QINV, a2v[1][o+2]*QINV, a2v[1][o+3]*QINV);
    st4b(R+12, a2v[2][o]*QINV, a2v[2][o+1]*QINV, a2v[2][o+2]*QINV, a2v[2][o+3]*QINV);
  }

  float fsv[16], fvv[48];
  {
    const float* fr = ff + (size_t)n*64;
    #pragma unroll
    for (int q = 0; q < 4; ++q) {
      const float4 t = ld4(fr + q*4);
      fsv[q*4]=t.x; fsv[q*4+1]=t.y; fsv[q*4+2]=t.z; fsv[q*4+3]=t.w;
    }
    #pragma unroll
    for (int q = 0; q < 12; ++q) {
      const float4 t = ld4(fr + 16 + q*4);
      fvv[q*4]=t.x; fvv[q*4+1]=t.y; fvv[q*4+2]=t.z; fvv[q*4+3]=t.w;
    }
  }

  if (p == 0) {
    float m0=0.f, m1=0.f, m2=0.f;
    #pragma unroll
    for (int v = 0; v < 16; ++v) {
      m0 += t1[v]*fvv[v*3]; m1 += t1[v]*fvv[v*3+1]; m2 += t1[v]*fvv[v*3+2];
    }
    for (int u = 0; u < 64; ++u) {
      float t2 = 0.f;
      #pragma unroll
      for (int q = 0; q < 4; ++q) {
        const float4 w = ld4(Wmvs + u*16 + q*4);
        t2 += w.x*fsv[q*4] + w.y*fsv[q*4+1] + w.z*fsv[q*4+2] + w.w*fsv[q*4+3];
      }
      m0 += nrow[64+u*3+0]*t2;
      m1 += nrow[64+u*3+1]*t2;
      m2 += nrow[64+u*3+2]*t2;
    }
    float* o = out + (size_t)n*4;
    o[0] = 0.f;
    o[1] = MPSC*m0; o[2] = MPSC*m1; o[3] = MPSC*m2;
  }

  float gsA[16], gsB[16], gvA[48], gvB[48];
  #pragma unroll
  for (int up = 0; up < 16; ++up) {
    float sA=0.f,sB=0.f,vA0=0.f,vA1=0.f,vA2=0.f,vB0=0.f,vB1=0.f,vB2=0.f;
    #pragma unroll
    for (int q = 0; q < 4; ++q) {
      const float4 w0 = ld4(Wfs0 + up*16 + q*4);
      const float4 w1 = ld4(Wfs1 + up*16 + q*4);
      const float4 w2 = ld4(Wfr0 + up*16 + q*4);
      const float4 w3 = ld4(Wfr1 + up*16 + q*4);
      #pragma unroll
      for (int d = 0; d < 4; ++d) {
        const int v = q*4+d;
        sA  += C4(w0,d)*fsv[v];
        sB  += C4(w2,d)*fsv[v];
        vA0 += C4(w1,d)*fvv[v*3]; vA1 += C4(w1,d)*fvv[v*3+1]; vA2 += C4(w1,d)*fvv[v*3+2];
        vB0 += C4(w3,d)*fvv[v*3]; vB1 += C4(w3,d)*fvv[v*3+1]; vB2 += C4(w3,d)*fvv[v*3+2];
      }
    }
    gsA[up]=sA; gsB[up]=sB;
    gvA[up*3]=vA0; gvA[up*3+1]=vA1; gvA[up*3+2]=vA2;
    gvB[up*3]=vB0; gvB[up*3+1]=vB1; gvB[up*3+2]=vB2;
  }

  #pragma unroll
  for (int tq = 0; tq < 4; ++tq) {
    float qa[4], qb[4], ra[3][4], rb[3][4];
    #pragma unroll
    for (int d = 0; d < 4; ++d) {
      const int U = p*16 + tq*4 + d;
      float aq=0.f,bq=0.f,a0=0.f,a1=0.f,a2=0.f,b0=0.f,b1=0.f,b2=0.f;
      #pragma unroll
      for (int q = 0; q < 4; ++q) {
        const float4 ws_ = ld4(Wvss + U*16 + q*4);
        const float4 wr_ = ld4(Wvrs + U*16 + q*4);
        const float4 wv_ = ld4(Wvsv + U*16 + q*4);
        const float4 wu_ = ld4(Wvrv + U*16 + q*4);
        #pragma unroll
        for (int dd = 0; dd < 4; ++dd) {
          const int up = q*4+dd;
          aq += C4(ws_,dd)*gsA[up];
          bq += C4(wr_,dd)*gsB[up];
          a0 += C4(wv_,dd)*gvA[up*3]; a1 += C4(wv_,dd)*gvA[up*3+1]; a2 += C4(wv_,dd)*gvA[up*3+2];
          b0 += C4(wu_,dd)*gvB[up*3]; b1 += C4(wu_,dd)*gvB[up*3+1]; b2 += C4(wu_,dd)*gvB[up*3+2];
        }
      }
      qa[d]=aq; qb[d]=bq;
      ra[0][d]=a0*ISQ3; ra[1][d]=a1*ISQ3; ra[2][d]=a2*ISQ3;
      rb[0][d]=b0*ISQ3; rb[1][d]=b1*ISQ3; rb[2][d]=b2*ISQ3;
    }
    if (p < 4) {
      const int uq = p*4 + tq;
      unsigned short* S = wsS + rec + uq*48;
      unsigned short* R = wsR + rec + uq*48;
      st4b(S+16, qa[0],qa[1],qa[2],qa[3]);
      st4b(S+24, ra[0][0],ra[0][1],ra[0][2],ra[0][3]);
      st4b(S+28, ra[1][0],ra[1][1],ra[1][2],ra[1][3]);
      st4b(S+32, ra[2][0],ra[2][1],ra[2][2],ra[2][3]);
      st4b(R+16, qb[0],qb[1],qb[2],qb[3]);
      st4b(R+24, rb[0][0],rb[0][1],rb[0][2],rb[0][3]);
      st4b(R+28, rb[1][0],rb[1][1],rb[1][2],rb[1][3]);
      st4b(R+32, rb[2][0],rb[2][1],rb[2][2],rb[2][3]);
    } else {
      const int uq = (p-4)*4 + tq;
      unsigned short* S = wsS + rec + uq*48;
      unsigned short* R = wsR + rec + uq*48;
      st4b(S+20, qa[0]*ISQ3,qa[1]*ISQ3,qa[2]*ISQ3,qa[3]*ISQ3);
      st4b(S+36, ra[0][0],ra[0][1],ra[0][2],ra[0][3]);
      st4b(S+40, ra[1][0],ra[1][1],ra[1][2],ra[1][3]);
      st4b(S+44, ra[2][0],ra[2][1],ra[2][2],ra[2][3]);
      st4b(R+20, qb[0]*ISQ3,qb[1]*ISQ3,qb[2]*ISQ3,qb[3]*ISQ3);
      st4b(R+36, rb[0][0],rb[0][1],rb[0][2],rb[0][3]);
      st4b(R+40, rb[1][0],rb[1][1],rb[1][2],rb[1][3]);
      st4b(R+44, rb[2][0],rb[2][1],rb[2][2],rb[2][3]);
    }
  }
}

extern "C" void kernel_launch(void* const* d_in, const int* in_sizes, int n_in,
                              void* d_out, int out_size, void* d_ws, size_t ws_size,
                              hipStream_t stream) {
  (void)in_sizes; (void)n_in; (void)out_size; (void)ws_size;
  const float* node_feats  = (const float*)d_in[1];
  const float* edge_attrs  = (const float*)d_in[2];
  const float* edge_feats  = (const float*)d_in[3];
  const float* field_feats = (const float*)d_in[4];
  const int*   edge_index  = (const int*)  d_in[5];
  const float* W1s  = (const float*)d_in[6];
  const float* W1v  = (const float*)d_in[7];
  const float* W2s  = (const float*)d_in[8];
  const float* W2v  = (const float*)d_in[9];
  const float* mw1  = (const float*)d_in[10];
  const float* mw2  = (const float*)d_in[11];
  const float* mw3  = (const float*)d_in[12];
  const float* mw4  = (const float*)d_in[13];
  const float* Wvss = (const float*)d_in[14];
  const float* Wvsv = (const float*)d_in[15];
  const float* Wvrs = (const float*)d_in[16];
  const float* Wvrv = (const float*)d_in[17];
  const float* Wfs0 = (const float*)d_in[18];
  const float* Wfs1 = (const float*)d_in[19];
  const float* Wfr0 = (const float*)d_in[20];
  const float* Wfr1 = (const float*)d_in[21];
  // d_in[22]/d_in[23] feed only mp0 which charges overwrite -> dead.
  const float* Wmsv = (const float*)d_in[24];
  const float* Wmvs = (const float*)d_in[25];

  float* out = (float*)d_out;
  unsigned short* wsS = (unsigned short*)d_ws;            // NN*768 bf16 (15.36 MB)
  unsigned short* wsR = wsS + (size_t)NN*768;             // NN*768 bf16

  hipLaunchKernelGGL(node_kernel, dim3(314), dim3(256), 0, stream,
      node_feats, field_feats, W1s, W1v, W2s, W2v, Wvss, Wvsv, Wvrs, Wvrv,
      Wfs0, Wfs1, Wfr0, Wfr1, Wmsv, Wmvs, wsS, wsR, out);
  hipLaunchKernelGGL(edge_fused_kernel, dim3(NE/128), dim3(256), 0, stream,
      edge_feats, mw1, mw2, mw3, mw4, edge_attrs, edge_index, wsS, wsR, out);
}

// Round 19
// 212.213 us; speedup vs baseline: 1.2297x; 1.0248x over previous
//
#include <hip/hip_runtime.h>

#define NN 10000
#define NE 160000

#define INV8   0.35355339059327373f   // 1/sqrt(8)
#define QINV   0.125f                 // 1/sqrt(64)
#define GAIN   1.679177f
#define ISQ3   0.57735026918962576f   // 1/sqrt(3)
#define FINALS 4.8828125e-5f          // 0.1 * (1/sqrt(512)) * (1/sqrt(128)) * 0.125(=tp_w's 1/sqrt64)
#define MPSC   2.2097086912079612e-4f // 0.01 / sqrt(2048)

typedef __attribute__((ext_vector_type(8))) short bf16x8;
typedef __attribute__((ext_vector_type(4))) float f32x4;

__device__ __forceinline__ float4 ld4(const float* p){ return *(const float4*)p; }
__device__ __forceinline__ float sil(float x){ return x*GAIN/(1.f+__expf(-x)); }
__device__ __forceinline__ unsigned short f2b(float f){   // f32 -> bf16 RNE
  unsigned u = __float_as_uint(f);
  return (unsigned short)((u + 0x7FFFu + ((u>>16)&1u)) >> 16);
}
__device__ __forceinline__ float b2f(unsigned short b){
  return __uint_as_float(((unsigned)b) << 16);
}
__device__ __forceinline__ void st4b(unsigned short* p, float a, float b, float c, float d){
  unsigned long long v = (unsigned long long)f2b(a)
                       | ((unsigned long long)f2b(b) << 16)
                       | ((unsigned long long)f2b(c) << 32)
                       | ((unsigned long long)f2b(d) << 48);
  *(unsigned long long*)p = v;
}
__device__ __forceinline__ void up8(const unsigned short* p, float* f){
  const uint4 v = *(const uint4*)p;
  f[0]=__uint_as_float(v.x<<16); f[1]=__uint_as_float(v.x&0xFFFF0000u);
  f[2]=__uint_as_float(v.y<<16); f[3]=__uint_as_float(v.y&0xFFFF0000u);
  f[4]=__uint_as_float(v.z<<16); f[5]=__uint_as_float(v.z&0xFFFF0000u);
  f[6]=__uint_as_float(v.w<<16); f[7]=__uint_as_float(v.w&0xFFFF0000u);
}
#define C4(v,i) (((const float*)&(v))[i])

// ======= fused edge kernel: 64 edges/block, 41 KB LDS -> 3 blocks/CU =======
// Pool: W4q @0 (8KB). Region @8192: MLP phases use W1t(4K)@8192, W2t(8K)@12288,
// W3t(8K)@20480, H(8K)@28672 (28K). L4+combine reuse region as WQ[64][260] (33KB).
#define WQ_STRIDE 260
__global__ __launch_bounds__(256, 3) void edge_fused_kernel(
    const float* __restrict__ efe,
    const float* __restrict__ mw1, const float* __restrict__ mw2,
    const float* __restrict__ mw3, const float* __restrict__ mw4,
    const float* __restrict__ ea, const int* __restrict__ eidx,
    const unsigned short* __restrict__ wsS, const unsigned short* __restrict__ wsR,
    float* __restrict__ out)
{
  __shared__ __align__(16) unsigned char pool[8192 + 64*WQ_STRIDE*2];
  unsigned short* W4q = (unsigned short*)pool;             // 8 KB
  unsigned short* W1t = (unsigned short*)(pool + 8192);    // 4 KB
  unsigned short* W2t = (unsigned short*)(pool + 12288);   // 8 KB
  unsigned short* W3t = (unsigned short*)(pool + 20480);   // 8 KB
  unsigned short* H   = (unsigned short*)(pool + 28672);   // 8 KB
  unsigned short* WQ  = (unsigned short*)(pool + 8192);    // 33 KB (overlaps W1t..H)

  const int tid = threadIdx.x;
  const int wv  = tid >> 6;
  const int l   = tid & 63;
  const int eb  = blockIdx.x * 64;

  // ---- stage X0 -> H (64e x 32k) + W1t/W2t/W3t ----
  #pragma unroll
  for (int it = 0; it < 8; ++it) {
    const int i = tid + 256*it, e = i >> 5, k = i & 31;
    H[e*64 + (k ^ ((e&7)<<3))] = (k < 8) ? f2b(efe[(size_t)(eb+e)*8 + k]) : 0;
  }
  #pragma unroll
  for (int it = 0; it < 8; ++it) {
    const int i = tid + 256*it, n = i >> 5, k = i & 31;
    W1t[n*32 + (k ^ ((n&3)<<3))] = (k < 8) ? f2b(mw1[k*64 + n]) : 0;
  }
  #pragma unroll
  for (int it = 0; it < 16; ++it) {
    const int i = tid + 256*it, k = i >> 6, n = i & 63;
    W2t[n*64 + (k ^ ((n&7)<<3))] = f2b(mw2[k*64 + n]);
    W3t[n*64 + (k ^ ((n&7)<<3))] = f2b(mw3[k*64 + n]);
  }
  __syncthreads();

  const int arow = l & 15;
  const int koff = (l >> 4) * 8;

  // ---- L1: 4 M-frags ----
  {
    bf16x8 a[4];
    #pragma unroll
    for (int mf = 0; mf < 4; ++mf) {
      const int e = mf*16 + arow;
      a[mf] = *(const bf16x8*)&H[e*64 + (koff ^ ((e&7)<<3))];
    }
    const int n = wv*16 + arow;
    const bf16x8 b = *(const bf16x8*)&W1t[n*32 + (koff ^ ((n&3)<<3))];
    __syncthreads();
    f32x4 acc[4];
    #pragma unroll
    for (int mf = 0; mf < 4; ++mf) {
      acc[mf] = (f32x4){0.f,0.f,0.f,0.f};
      acc[mf] = __builtin_amdgcn_mfma_f32_16x16x32_bf16(a[mf], b, acc[mf], 0, 0, 0);
    }
    #pragma unroll
    for (int mf = 0; mf < 4; ++mf)
      #pragma unroll
      for (int rg = 0; rg < 4; ++rg) {
        const int e = mf*16 + (l>>4)*4 + rg, j = wv*16 + arow;
        H[e*64 + (j ^ ((e&7)<<3))] = f2b(sil(acc[mf][rg]*INV8));
      }
    __syncthreads();
  }

  // ---- L2, L3 ----
  const unsigned short* Wt[2] = { W2t, W3t };
  #pragma unroll
  for (int ly = 0; ly < 2; ++ly) {
    bf16x8 a[8];
    #pragma unroll
    for (int mf = 0; mf < 4; ++mf)
      #pragma unroll
      for (int ks = 0; ks < 2; ++ks) {
        const int e = mf*16 + arow, kb = ks*32 + koff;
        a[mf*2+ks] = *(const bf16x8*)&H[e*64 + (kb ^ ((e&7)<<3))];
      }
    const int n = wv*16 + arow;
    bf16x8 b0, b1;
    {
      const int kb0 = koff, kb1 = 32 + koff;
      b0 = *(const bf16x8*)&Wt[ly][n*64 + (kb0 ^ ((n&7)<<3))];
      b1 = *(const bf16x8*)&Wt[ly][n*64 + (kb1 ^ ((n&7)<<3))];
    }
    __syncthreads();
    f32x4 acc[4];
    #pragma unroll
    for (int mf = 0; mf < 4; ++mf) {
      acc[mf] = (f32x4){0.f,0.f,0.f,0.f};
      acc[mf] = __builtin_amdgcn_mfma_f32_16x16x32_bf16(a[mf*2+0], b0, acc[mf], 0, 0, 0);
      acc[mf] = __builtin_amdgcn_mfma_f32_16x16x32_bf16(a[mf*2+1], b1, acc[mf], 0, 0, 0);
    }
    #pragma unroll
    for (int mf = 0; mf < 4; ++mf)
      #pragma unroll
      for (int rg = 0; rg < 4; ++rg) {
        const int e = mf*16 + (l>>4)*4 + rg, j = wv*16 + arow;
        H[e*64 + (j ^ ((e&7)<<3))] = f2b(sil(acc[mf][rg]*QINV));
      }
    __syncthreads();
  }

  // ---- h3 -> registers (frees H for WQ overlay) ----
  bf16x8 a4[8];
  #pragma unroll
  for (int mf = 0; mf < 4; ++mf)
    #pragma unroll
    for (int ks = 0; ks < 2; ++ks) {
      const int e = mf*16 + arow, kb = ks*32 + koff;
      a4[mf*2+ks] = *(const bf16x8*)&H[e*64 + (kb ^ ((e&7)<<3))];
    }

  // ---- L4 quarters -> WQ (LDS), RAW (1/sqrt64 lives in FINALS) ----
  for (int q = 0; q < 4; ++q) {
    #pragma unroll
    for (int it = 0; it < 16; ++it) {
      const int i = tid + 256*it, k = i >> 6, nn = i & 63;
      W4q[nn*64 + (k ^ ((nn&7)<<3))] = f2b(mw4[k*256 + q*64 + nn]);
    }
    __syncthreads();

    const int n = wv*16 + arow;
    const bf16x8 b0 = *(const bf16x8*)&W4q[n*64 + ((koff     ) ^ ((n&7)<<3))];
    const bf16x8 b1 = *(const bf16x8*)&W4q[n*64 + ((32 + koff) ^ ((n&7)<<3))];
    f32x4 acc[4];
    #pragma unroll
    for (int mf = 0; mf < 4; ++mf) {
      acc[mf] = (f32x4){0.f,0.f,0.f,0.f};
      acc[mf] = __builtin_amdgcn_mfma_f32_16x16x32_bf16(a4[mf*2+0], b0, acc[mf], 0, 0, 0);
      acc[mf] = __builtin_amdgcn_mfma_f32_16x16x32_bf16(a4[mf*2+1], b1, acc[mf], 0, 0, 0);
    }
    #pragma unroll
    for (int mf = 0; mf < 4; ++mf)
      #pragma unroll
      for (int rg = 0; rg < 4; ++rg) {
        const int e = mf*16 + (l>>4)*4 + rg;
        const int j = q*64 + wv*16 + arow;
        WQ[e*WQ_STRIDE + j] = f2b(acc[mf][rg]);
      }
    __syncthreads();
  }

  // ---- combine phase: 4 threads/edge (sub = uq quarter), wq from LDS ----
  {
    const int el  = tid >> 2;
    const int sub = tid & 3;
    const int e   = eb + el;
    const int s = eidx[e];
    const int r = eidx[NE + e];
    const float4 y = ld4(ea + (size_t)e*4);

    float accS = 0.f, accR = 0.f;
    const unsigned short* Sb = wsS + (size_t)s*768 + sub*192;
    const unsigned short* Rb = wsR + (size_t)r*768 + sub*192;
    const unsigned short* wrow = WQ + el*WQ_STRIDE;
    #pragma unroll 2
    for (int t = 0; t < 4; ++t) {
      const int uq = sub*4 + t;
      const unsigned short* Sr = Sb + t*48;
      const unsigned short* Rr = Rb + t*48;
      float S[48], R[48];
      up8(Sr+ 0, S+ 0); up8(Sr+ 8, S+ 8); up8(Sr+16, S+16);
      up8(Sr+24, S+24); up8(Sr+32, S+32); up8(Sr+40, S+40);
      up8(Rr+ 0, R+ 0); up8(Rr+ 8, R+ 8); up8(Rr+16, R+16);
      up8(Rr+24, R+24); up8(Rr+32, R+32); up8(Rr+40, R+40);

      float wq[16];
      #pragma unroll
      for (int m = 0; m < 4; ++m) {
        const unsigned long long v = *(const unsigned long long*)(wrow + m*64 + uq*4);
        #pragma unroll
        for (int d = 0; d < 4; ++d)
          wq[m*4+d] = b2f((unsigned short)(v >> (16*d)));
      }

      #pragma unroll
      for (int d = 0; d < 4; ++d) {
        const float bs = S[d]    + R[d];
        const float b0 = S[4+d]  + R[4+d];
        const float b1 = S[8+d]  + R[8+d];
        const float b2 = S[12+d] + R[12+d];
        const float bvy = b0*y.y + b1*y.z + b2*y.w;
        const float m0 = wq[d]    * bs * y.x;
        const float m1 = wq[4+d]  * bvy;
        const float m2 = wq[8+d]  * bs;
        const float m3 = wq[12+d] * y.x;
        accS += m0*S[16+d] + m1*S[20+d]
              + m2*(y.y*S[24+d] + y.z*S[28+d] + y.w*S[32+d])
              + m3*(b0*S[36+d] + b1*S[40+d] + b2*S[44+d]);
        accR += m0*R[16+d] + m1*R[20+d]
              + m2*(y.y*R[24+d] + y.z*R[28+d] + y.w*R[32+d])
              + m3*(b0*R[36+d] + b1*R[40+d] + b2*R[44+d]);
      }
    }
    float acc = FINALS * (accS + accR);
    acc += __shfl_xor(acc, 1, 64);
    acc += __shfl_xor(acc, 2, 64);
    if (sub == 0) {
      out[NN*4 + e] = acc;
      atomicAdd(out + (size_t)r*4, acc);
      atomicAdd(out + (size_t)s*4, -acc);
    }
  }
}

// ============ node kernel (round-8 verbatim, proven 73 µs) ============
__global__ __launch_bounds__(256) void node_kernel(
    const float* __restrict__ nf, const float* __restrict__ ff,
    const float* __restrict__ W1s, const float* __restrict__ W1v,
    const float* __restrict__ W2s, const float* __restrict__ W2v,
    const float* __restrict__ Wvss, const float* __restrict__ Wvsv,
    const float* __restrict__ Wvrs, const float* __restrict__ Wvrv,
    const float* __restrict__ Wfs0, const float* __restrict__ Wfs1,
    const float* __restrict__ Wfr0, const float* __restrict__ Wfr1,
    const float* __restrict__ Wmsv, const float* __restrict__ Wmvs,
    unsigned short* __restrict__ wsS, unsigned short* __restrict__ wsR,
    float* __restrict__ out)
{
  const int lane = threadIdx.x & 63;
  const int Wid  = blockIdx.x * 4 + (threadIdx.x >> 6);
  const int p    = __builtin_amdgcn_readfirstlane(Wid & 7);
  const int grp  = __builtin_amdgcn_readfirstlane(Wid >> 3);
  const int n = grp * 64 + lane;
  if (n >= NN) return;
  const float* nrow = nf + (size_t)n * 256;
  const int vb = p * 8;
  const size_t rec = (size_t)n * 768;

  float a1s[8], a2s[8], a1v[3][8], a2v[3][8], t1[16];
  #pragma unroll
  for (int j = 0; j < 8; ++j){ a1s[j]=0.f; a2s[j]=0.f;
    a1v[0][j]=0.f; a1v[1][j]=0.f; a1v[2][j]=0.f;
    a2v[0][j]=0.f; a2v[1][j]=0.f; a2v[2][j]=0.f; }
  #pragma unroll
  for (int j = 0; j < 16; ++j) t1[j]=0.f;

  for (int u = 0; u < 64; ++u) {
    const float su  = nrow[u];
    const float nv0 = nrow[64+u*3+0];
    const float nv1 = nrow[64+u*3+1];
    const float nv2 = nrow[64+u*3+2];
    const float4 s1a = ld4(W1s+u*64+vb), s1b = ld4(W1s+u*64+vb+4);
    const float4 s2a = ld4(W2s+u*64+vb), s2b = ld4(W2s+u*64+vb+4);
    const float4 v1a = ld4(W1v+u*64+vb), v1b = ld4(W1v+u*64+vb+4);
    const float4 v2a = ld4(W2v+u*64+vb), v2b = ld4(W2v+u*64+vb+4);
    #pragma unroll
    for (int d = 0; d < 4; ++d) {
      a1s[d]     += su*C4(s1a,d);  a1s[4+d]     += su*C4(s1b,d);
      a2s[d]     += su*C4(s2a,d);  a2s[4+d]     += su*C4(s2b,d);
      a1v[0][d]  += nv0*C4(v1a,d); a1v[0][4+d]  += nv0*C4(v1b,d);
      a1v[1][d]  += nv1*C4(v1a,d); a1v[1][4+d]  += nv1*C4(v1b,d);
      a1v[2][d]  += nv2*C4(v1a,d); a1v[2][4+d]  += nv2*C4(v1b,d);
      a2v[0][d]  += nv0*C4(v2a,d); a2v[0][4+d]  += nv0*C4(v2b,d);
      a2v[1][d]  += nv1*C4(v2a,d); a2v[1][4+d]  += nv1*C4(v2b,d);
      a2v[2][d]  += nv2*C4(v2a,d); a2v[2][4+d]  += nv2*C4(v2b,d);
    }
    if (p == 0) {
      #pragma unroll
      for (int q = 0; q < 4; ++q) {
        const float4 m = ld4(Wmsv + u*16 + q*4);
        t1[q*4]   += su*m.x; t1[q*4+1] += su*m.y;
        t1[q*4+2] += su*m.z; t1[q*4+3] += su*m.w;
      }
    }
  }
  #pragma unroll
  for (int hh = 0; hh < 2; ++hh) {
    const int uq = 2*p + hh, o = hh*4;
    unsigned short* S = wsS + rec + uq*48;
    unsigned short* R = wsR + rec + uq*48;
    st4b(S+0,  a1s[o]*QINV, a1s[o+1]*QINV, a1s[o+2]*QINV, a1s[o+3]*QINV);
    st4b(S+4,  a1v[0][o]*QINV, a1v[0][o+1]*QINV, a1v[0][o+2]*QINV, a1v[0][o+3]*QINV);
    st4b(S+8,  a1v[1][o]*QINV, a1v[1][o+1]*QINV, a1v[1][o+2]*QINV, a1v[1][o+3]*QINV);
    st4b(S+12, a1v[2][o]*QINV, a1v[2][o+1]*QINV, a1v[2][o+2]*QINV, a1v[2][o+3]*QINV);
    st4b(R+0,  a2s[o]*QINV, a2s[o+1]*QINV, a2s[o+2]*QINV, a2s[o+3]*QINV);
    st4b(R+4,  a2v[0][o]*QINV, a2v[0][o+1]*QINV, a2v[0][o+2]*QINV, a2v[0][o+3]*QINV);
    st4b(R+8,  a2v[1][o]*QINV, a2v[1][o+1]*QINV, a2v[1][o+2]*QINV, a2v[1][o+3]*QINV);
    st4b(R+12, a2v[2][o]*QINV, a2v[2][o+1]*QINV, a2v[2][o+2]*QINV, a2v[2][o+3]*QINV);
  }

  float fsv[16], fvv[48];
  {
    const float* fr = ff + (size_t)n*64;
    #pragma unroll
    for (int q = 0; q < 4; ++q) {
      const float4 t = ld4(fr + q*4);
      fsv[q*4]=t.x; fsv[q*4+1]=t.y; fsv[q*4+2]=t.z; fsv[q*4+3]=t.w;
    }
    #pragma unroll
    for (int q = 0; q < 12; ++q) {
      const float4 t = ld4(fr + 16 + q*4);
      fvv[q*4]=t.x; fvv[q*4+1]=t.y; fvv[q*4+2]=t.z; fvv[q*4+3]=t.w;
    }
  }

  if (p == 0) {
    float m0=0.f, m1=0.f, m2=0.f;
    #pragma unroll
    for (int v = 0; v < 16; ++v) {
      m0 += t1[v]*fvv[v*3]; m1 += t1[v]*fvv[v*3+1]; m2 += t1[v]*fvv[v*3+2];
    }
    for (int u = 0; u < 64; ++u) {
      float t2 = 0.f;
      #pragma unroll
      for (int q = 0; q < 4; ++q) {
        const float4 w = ld4(Wmvs + u*16 + q*4);
        t2 += w.x*fsv[q*4] + w.y*fsv[q*4+1] + w.z*fsv[q*4+2] + w.w*fsv[q*4+3];
      }
      m0 += nrow[64+u*3+0]*t2;
      m1 += nrow[64+u*3+1]*t2;
      m2 += nrow[64+u*3+2]*t2;
    }
    float* o = out + (size_t)n*4;
    o[0] = 0.f;
    o[1] = MPSC*m0; o[2] = MPSC*m1; o[3] = MPSC*m2;
  }

  float gsA[16], gsB[16], gvA[48], gvB[48];
  #pragma unroll
  for (int up = 0; up < 16; ++up) {
    float sA=0.f,sB=0.f,vA0=0.f,vA1=0.f,vA2=0.f,vB0=0.f,vB1=0.f,vB2=0.f;
    #pragma unroll
    for (int q = 0; q < 4; ++q) {
      const float4 w0 = ld4(Wfs0 + up*16 + q*4);
      const float4 w1 = ld4(Wfs1 + up*16 + q*4);
      const float4 w2 = ld4(Wfr0 + up*16 + q*4);
      const float4 w3 = ld4(Wfr1 + up*16 + q*4);
      #pragma unroll
      for (int d = 0; d < 4; ++d) {
        const int v = q*4+d;
        sA  += C4(w0,d)*fsv[v];
        sB  += C4(w2,d)*fsv[v];
        vA0 += C4(w1,d)*fvv[v*3]; vA1 += C4(w1,d)*fvv[v*3+1]; vA2 += C4(w1,d)*fvv[v*3+2];
        vB0 += C4(w3,d)*fvv[v*3]; vB1 += C4(w3,d)*fvv[v*3+1]; vB2 += C4(w3,d)*fvv[v*3+2];
      }
    }
    gsA[up]=sA; gsB[up]=sB;
    gvA[up*3]=vA0; gvA[up*3+1]=vA1; gvA[up*3+2]=vA2;
    gvB[up*3]=vB0; gvB[up*3+1]=vB1; gvB[up*3+2]=vB2;
  }

  #pragma unroll
  for (int tq = 0; tq < 4; ++tq) {
    float qa[4], qb[4], ra[3][4], rb[3][4];
    #pragma unroll
    for (int d = 0; d < 4; ++d) {
      const int U = p*16 + tq*4 + d;
      float aq=0.f,bq=0.f,a0=0.f,a1=0.f,a2=0.f,b0=0.f,b1=0.f,b2=0.f;
      #pragma unroll
      for (int q = 0; q < 4; ++q) {
        const float4 ws_ = ld4(Wvss + U*16 + q*4);
        const float4 wr_ = ld4(Wvrs + U*16 + q*4);
        const float4 wv_ = ld4(Wvsv + U*16 + q*4);
        const float4 wu_ = ld4(Wvrv + U*16 + q*4);
        #pragma unroll
        for (int dd = 0; dd < 4; ++dd) {
          const int up = q*4+dd;
          aq += C4(ws_,dd)*gsA[up];
          bq += C4(wr_,dd)*gsB[up];
          a0 += C4(wv_,dd)*gvA[up*3]; a1 += C4(wv_,dd)*gvA[up*3+1]; a2 += C4(wv_,dd)*gvA[up*3+2];
          b0 += C4(wu_,dd)*gvB[up*3]; b1 += C4(wu_,dd)*gvB[up*3+1]; b2 += C4(wu_,dd)*gvB[up*3+2];
        }
      }
      qa[d]=aq; qb[d]=bq;
      ra[0][d]=a0*ISQ3; ra[1][d]=a1*ISQ3; ra[2][d]=a2*ISQ3;
      rb[0][d]=b0*ISQ3; rb[1][d]=b1*ISQ3; rb[2][d]=b2*ISQ3;
    }
    if (p < 4) {
      const int uq = p*4 + tq;
      unsigned short* S = wsS + rec + uq*48;
      unsigned short* R = wsR + rec + uq*48;
      st4b(S+16, qa[0],qa[1],qa[2],qa[3]);
      st4b(S+24, ra[0][0],ra[0][1],ra[0][2],ra[0][3]);
      st4b(S+28, ra[1][0],ra[1][1],ra[1][2],ra[1][3]);
      st4b(S+32, ra[2][0],ra[2][1],ra[2][2],ra[2][3]);
      st4b(R+16, qb[0],qb[1],qb[2],qb[3]);
      st4b(R+24, rb[0][0],rb[0][1],rb[0][2],rb[0][3]);
      st4b(R+28, rb[1][0],rb[1][1],rb[1][2],rb[1][3]);
      st4b(R+32, rb[2][0],rb[2][1],rb[2][2],rb[2][3]);
    } else {
      const int uq = (p-4)*4 + tq;
      unsigned short* S = wsS + rec + uq*48;
      unsigned short* R = wsR + rec + uq*48;
      st4b(S+20, qa[0]*ISQ3,qa[1]*ISQ3,qa[2]*ISQ3,qa[3]*ISQ3);
      st4b(S+36, ra[0][0],ra[0][1],ra[0][2],ra[0][3]);
      st4b(S+40, ra[1][0],ra[1][1],ra[1][2],ra[1][3]);
      st4b(S+44, ra[2][0],ra[2][1],ra[2][2],ra[2][3]);
      st4b(R+20, qb[0]*ISQ3,qb[1]*ISQ3,qb[2]*ISQ3,qb[3]*ISQ3);
      st4b(R+36, rb[0][0],rb[0][1],rb[0][2],rb[0][3]);
      st4b(R+40, rb[1][0],rb[1][1],rb[1][2],rb[1][3]);
      st4b(R+44, rb[2][0],rb[2][1],rb[2][2],rb[2][3]);
    }
  }
}

extern "C" void kernel_launch(void* const* d_in, const int* in_sizes, int n_in,
                              void* d_out, int out_size, void* d_ws, size_t ws_size,
                              hipStream_t stream) {
  (void)in_sizes; (void)n_in; (void)out_size; (void)ws_size;
  const float* node_feats  = (const float*)d_in[1];
  const float* edge_attrs  = (const float*)d_in[2];
  const float* edge_feats  = (const float*)d_in[3];
  const float* field_feats = (const float*)d_in[4];
  const int*   edge_index  = (const int*)  d_in[5];
  const float* W1s  = (const float*)d_in[6];
  const float* W1v  = (const float*)d_in[7];
  const float* W2s  = (const float*)d_in[8];
  const float* W2v  = (const float*)d_in[9];
  const float* mw1  = (const float*)d_in[10];
  const float* mw2  = (const float*)d_in[11];
  const float* mw3  = (const float*)d_in[12];
  const float* mw4  = (const float*)d_in[13];
  const float* Wvss = (const float*)d_in[14];
  const float* Wvsv = (const float*)d_in[15];
  const float* Wvrs = (const float*)d_in[16];
  const float* Wvrv = (const float*)d_in[17];
  const float* Wfs0 = (const float*)d_in[18];
  const float* Wfs1 = (const float*)d_in[19];
  const float* Wfr0 = (const float*)d_in[20];
  const float* Wfr1 = (const float*)d_in[21];
  // d_in[22]/d_in[23] feed only mp0 which charges overwrite -> dead.
  const float* Wmsv = (const float*)d_in[24];
  const float* Wmvs = (const float*)d_in[25];

  float* out = (float*)d_out;
  unsigned short* wsS = (unsigned short*)d_ws;            // NN*768 bf16 (15.36 MB)
  unsigned short* wsR = wsS + (size_t)NN*768;             // NN*768 bf16

  hipLaunchKernelGGL(node_kernel, dim3(314), dim3(256), 0, stream,
      node_feats, field_feats, W1s, W1v, W2s, W2v, Wvss, Wvsv, Wvrs, Wvrv,
      Wfs0, Wfs1, Wfr0, Wfr1, Wmsv, Wmvs, wsS, wsR, out);
  hipLaunchKernelGGL(edge_fused_kernel, dim3(NE/64), dim3(256), 0, stream,
      edge_feats, mw1, mw2, mw3, mw4, edge_attrs, edge_index, wsS, wsR, out);
}